// Round 8
// baseline (119.424 us; speedup 1.0000x reference)
//
#include <hip/hip_runtime.h>

typedef _Float16 f16;
typedef _Float16 f16x8 __attribute__((ext_vector_type(8)));
typedef _Float16 f16x4 __attribute__((ext_vector_type(4)));
typedef float    f32x4 __attribute__((ext_vector_type(4)));

#define MFMA16(a, b, c) __builtin_amdgcn_mfma_f32_16x16x32_f16((a), (b), (c), 0, 0, 0)

// async global->LDS, 16B per lane; LDS dest is wave-uniform base + lane*16
__device__ __forceinline__ void gload16(const void* g, void* l) {
  __builtin_amdgcn_global_load_lds(
      (const __attribute__((address_space(1))) unsigned int*)g,
      (__attribute__((address_space(3))) unsigned int*)l, 16, 0, 0);
}

// raw v_exp_f32: computes 2^x (scores are kept in log2 domain)
__device__ __forceinline__ float ex2(float x) {
  float r;
  asm("v_exp_f32 %0, %1" : "=v"(r) : "v"(x));
  return r;
}

// ---------------- prep kernels ----------------

__global__ void cast_f32_f16(const float* __restrict__ in, f16* __restrict__ out, int n4) {
  int i = blockIdx.x * blockDim.x + threadIdx.x;
  if (i < n4) {
    float4 v = ((const float4*)in)[i];
    f16x4 o;
    o.x = (f16)v.x; o.y = (f16)v.y; o.z = (f16)v.z; o.w = (f16)v.w;
    ((f16x4*)out)[i] = o;
  }
}

// out[c][r] = (f16) in[r][c];  R rows, Cc cols of `in`; both multiples of 32
__global__ void transpose_cast(const float* __restrict__ in, f16* __restrict__ out, int R, int Cc) {
  __shared__ float tile[32][33];
  int c0 = blockIdx.x * 32, r0 = blockIdx.y * 32;
  int tx = threadIdx.x, ty = threadIdx.y;
#pragma unroll
  for (int i = ty; i < 32; i += 8)
    tile[i][tx] = in[(size_t)(r0 + i) * Cc + c0 + tx];
  __syncthreads();
#pragma unroll
  for (int i = ty; i < 32; i += 8)
    out[(size_t)(c0 + i) * R + r0 + tx] = (f16)tile[tx][i];
}

// ---------------- shared GEMM core (2-phase double-buffered) ----------------
// C[128x128] tile = A[bm*128.., K] * Bt[bn*128.., K]^T, K = KDIM, fp16 in, f32 acc.
// lA/lB are [2][128][64] f16 (32KB each). One barrier per K-step; STAGE(kt+1)
// is issued BEFORE computing kt so the vmcnt(0) drain at the end-of-iter
// barrier lands after ~the whole compute phase (T3-minimum 2-phase).
// LDS content swizzle: LDS(row, kb) = global(row, kb ^ ((row&7)<<4)) bytes.
template <int KDIM>
__device__ __forceinline__ void gemm_core(const f16* __restrict__ A, const f16* __restrict__ Bt,
                                          int bm, int bn, f16* lA, f16* lB, f32x4 acc[4][4]) {
  const int t = threadIdx.x, lane = t & 63, wave = t >> 6;
  const int wm = wave >> 1, wn = wave & 1;
  const int srow = lane >> 3;            // row within 8-row chunk
  const int skb = (lane & 7) * 16;       // byte offset within 128B row
  const int nkt = KDIM / 64;

  auto STAGE = [&](int buf, int kt) {
#pragma unroll
    for (int c = 0; c < 4; ++c) {
      int cc = c * 4 + wave;             // 0..15, wave-uniform
      int row = cc * 8 + srow;           // 0..127
      int kbs = skb ^ ((row & 7) << 4);  // pre-swizzled source byte offset
      gload16((const char*)A + (size_t)(bm * 128 + row) * (KDIM * 2) + kt * 128 + kbs,
              lA + buf * 8192 + cc * 512);
      gload16((const char*)Bt + (size_t)(bn * 128 + row) * (KDIM * 2) + kt * 128 + kbs,
              lB + buf * 8192 + cc * 512);
    }
  };

  STAGE(0, 0);
  __syncthreads();
  for (int kt = 0; kt < nkt; ++kt) {
    int cur = kt & 1;
    if (kt + 1 < nkt) STAGE(cur ^ 1, kt + 1);  // prefetch next K-step
    const f16* A0 = lA + cur * 8192;
    const f16* B0 = lB + cur * 8192;
    __builtin_amdgcn_s_setprio(1);
#pragma unroll
    for (int ks = 0; ks < 2; ++ks) {
      f16x8 af[4], bf[4];
#pragma unroll
      for (int mi = 0; mi < 4; ++mi) {
        int r = wm * 64 + mi * 16 + (lane & 15);
        int ke = (ks * 32 + ((lane >> 4) << 3)) ^ ((r & 7) << 3);  // elements
        af[mi] = *(const f16x8*)&A0[r * 64 + ke];
      }
#pragma unroll
      for (int ni = 0; ni < 4; ++ni) {
        int r = wn * 64 + ni * 16 + (lane & 15);
        int ke = (ks * 32 + ((lane >> 4) << 3)) ^ ((r & 7) << 3);
        bf[ni] = *(const f16x8*)&B0[r * 64 + ke];
      }
#pragma unroll
      for (int mi = 0; mi < 4; ++mi)
#pragma unroll
        for (int ni = 0; ni < 4; ++ni)
          acc[mi][ni] = MFMA16(af[mi], bf[ni], acc[mi][ni]);
    }
    __builtin_amdgcn_s_setprio(0);
    __syncthreads();  // drains prefetch (covered by compute); frees cur for kt+2
  }
}

// ---------------- QKV projection ----------------
// A = x_f16 [4096,1024]; Bt = w_qkv^T [3072,1024].
// sec0 -> Q[B,H,N,D]*0.125*log2(e) (scores end up in log2 domain) ;
// sec1 -> K[B,H,N,D] ;
// sec2 -> V^T[B,H,D,N] with key index permuted within 32-blocks:
//   p(n) = 8*((n>>2)&3) + 4*((n>>4)&1) + (n&3)
// so that attention's PV B-fragment is lane-local (see attn_one).
// Grid: 1D 768, XCD-chunked: XCD (w&7) owns an 8bm x 12bn tile chunk.
__global__ __launch_bounds__(256, 2) void gemm_qkv(const f16* __restrict__ A,
                                                   const f16* __restrict__ Bt,
                                                   f16* __restrict__ Qo, f16* __restrict__ Ko,
                                                   f16* __restrict__ Vt) {
  __shared__ __align__(16) f16 lA[2 * 8192];
  __shared__ __align__(16) f16 lB[2 * 8192];
  f32x4 acc[4][4] = {};
  int w = blockIdx.x;            // 0..767
  int xcd = w & 7, i = w >> 3;   // i in [0,96)
  int xr = xcd >> 1, xc = xcd & 1;
  int bm = xr * 8 + (i & 7);     // [0,32)
  int bn = xc * 12 + (i >> 3);   // [0,24)
  gemm_core<1024>(A, Bt, bm, bn, lA, lB, acc);
  int lane = threadIdx.x & 63, wave = threadIdx.x >> 6;
  int wm = wave >> 1, wn = wave & 1;
  int sec = (bn * 128) >> 10;  // 0=Q 1=K 2=V, uniform per block (128 | 1024)
  float scl = (sec == 0) ? 0.18033688f : 1.0f;  // 0.125 * log2(e)
#pragma unroll
  for (int mi = 0; mi < 4; ++mi)
#pragma unroll
    for (int ni = 0; ni < 4; ++ni)
#pragma unroll
      for (int reg = 0; reg < 4; ++reg) {
        int gr = bm * 128 + wm * 64 + mi * 16 + ((lane >> 4) << 2) + reg;  // [0,4096)
        int gc = bn * 128 + wn * 64 + ni * 16 + (lane & 15);               // [0,3072)
        int b = gr >> 11, n = gr & 2047;
        int jj = gc & 1023;
        int h = jj >> 6, d = jj & 63;
        f16 v = (f16)(acc[mi][ni][reg] * scl);
        size_t bh = (size_t)(b * 16 + h);
        if (sec == 0)      Qo[(bh * 2048 + n) * 64 + d] = v;
        else if (sec == 1) Ko[(bh * 2048 + n) * 64 + d] = v;
        else {
          int np = (n & ~31) | (((n >> 2) & 3) << 3) | (((n >> 4) & 1) << 2) | (n & 3);
          Vt[(bh * 64 + d) * 2048 + np] = v;
        }
      }
}

// ---------------- causal flash attention ----------------
// Q pre-scaled by 0.125*log2e (log2-domain scores). Q,K: [B,H,N,D] f16;
// Vt: [B,H,D,N] f16 (key-permuted); Ob: [N,C] slice.
// KV tiles of 128 keys: K LDS [128][64] (same swizzle/read as GEMM lA, 0-conflict);
// V LDS = two [64][64] sub-tiles. Two independent 64-key QK chains per iter give
// the SIMD ILP across the softmax dep chain; 1 barrier per 128 keys.
// Swapped-operand: S^T = mfma(K, Q); q = lane&15, k = kv0 + 16*ni + 4*(lane>>4) + reg.
__device__ __forceinline__ void attn_one(const f16* __restrict__ Qb, const f16* __restrict__ Kb,
                                         const f16* __restrict__ Vb, f16* __restrict__ Ob,
                                         int qt, int lane, int wave, f16* lK, f16* lV) {
  const int N = 2048;
  const int wq0 = qt * 64 + wave * 16;
  const int g = lane >> 4, q15 = lane & 15;
  f16x8 qf[2];
#pragma unroll
  for (int ks = 0; ks < 2; ++ks)
    qf[ks] = *(const f16x8*)&Qb[(size_t)(wq0 + q15) * 64 + ks * 32 + (g << 3)];
  f32x4 oacc[4] = {};
  float mrun = -1e30f, lrun = 0.f;
  const int srow = lane >> 3, skb = (lane & 7) * 16;
  const int ntiles = (qt >> 1) + 1;  // 128-key tiles

  auto STAGE = [&](int buf, int kv) {
    int kv0 = kv << 7;
#pragma unroll
    for (int c = 0; c < 4; ++c) {
      int cc = c * 4 + wave;             // 0..15, wave-uniform
      {  // K: rows 0..127 (keys), 128B each
        int row = cc * 8 + srow;
        int kbs = skb ^ ((row & 7) << 4);
        gload16((const char*)Kb + (size_t)(kv0 + row) * 128 + kbs, lK + buf * 8192 + cc * 512);
      }
      {  // V: sub-tile sv (keys kv0+64sv..+63), rows d 0..63, 128B each
        int sv = cc >> 3, c8 = cc & 7;
        int row = c8 * 8 + srow;
        int kbs = skb ^ ((row & 7) << 4);
        gload16((const char*)Vb + (size_t)row * (N * 2) + (size_t)(kv0 + sv * 64) * 2 + kbs,
                lV + buf * 8192 + sv * 4096 + c8 * 512);
      }
    }
  };

  STAGE(0, 0);
  __syncthreads();
  for (int kv = 0; kv < ntiles; ++kv) {
    int cur = kv & 1;
    if (kv + 1 < ntiles) STAGE(cur ^ 1, kv + 1);  // prefetch next tile
    const f16* K0 = lK + cur * 8192;
    const f16* V0 = lV + cur * 8192;
    int kv0 = kv << 7;
    f32x4 s[8] = {};
    __builtin_amdgcn_s_setprio(1);
#pragma unroll
    for (int ks = 0; ks < 2; ++ks) {
      f16x8 kf[8];
#pragma unroll
      for (int ni = 0; ni < 8; ++ni) {
        int r = ni * 16 + q15;                       // key row 0..127
        int ke = (ks * 32 + (g << 3)) ^ ((r & 7) << 3);
        kf[ni] = *(const f16x8*)&K0[r * 64 + ke];
      }
#pragma unroll
      for (int ni = 0; ni < 8; ++ni) s[ni] = MFMA16(kf[ni], qf[ks], s[ni]);  // S^T[k][q]
    }
    __builtin_amdgcn_s_setprio(0);
    if (kv == ntiles - 1) {  // last tile: causal mask. k = kv0+16ni+4g+reg, q = wq0+q15.
      int gq = wq0 + q15;
#pragma unroll
      for (int ni = 0; ni < 8; ++ni)
#pragma unroll
        for (int reg = 0; reg < 4; ++reg) {
          int gk = kv0 + ni * 16 + g * 4 + reg;
          if (gk > gq) s[ni][reg] = -1e30f;
        }
    }
    // per-lane max over 32 regs + 2 shfl (lanes l, l+16, l+32, l+48 share q)
    f32x4 m4 = s[0];
#pragma unroll
    for (int ni = 1; ni < 8; ++ni)
#pragma unroll
      for (int reg = 0; reg < 4; ++reg) m4[reg] = fmaxf(m4[reg], s[ni][reg]);
    float mx = fmaxf(fmaxf(m4[0], m4[1]), fmaxf(m4[2], m4[3]));
    mx = fmaxf(mx, __shfl_xor(mx, 16));
    mx = fmaxf(mx, __shfl_xor(mx, 32));
    // T13: rescale only if some row's running max grew (wave-uniform)
    if (__any(mx > mrun)) {
      float mnew = fmaxf(mrun, mx);
      float corr = ex2(mrun - mnew);
      mrun = mnew;
      lrun *= corr;
#pragma unroll
      for (int ni = 0; ni < 4; ++ni)
#pragma unroll
        for (int reg = 0; reg < 4; ++reg) oacc[ni][reg] *= corr;
    }
    float rsum = 0.f;
#pragma unroll
    for (int ni = 0; ni < 8; ++ni)
#pragma unroll
      for (int reg = 0; reg < 4; ++reg) {
        float p = ex2(s[ni][reg] - mrun);
        s[ni][reg] = p;
        rsum += p;
      }
    rsum += __shfl_xor(rsum, 16);
    rsum += __shfl_xor(rsum, 32);
    lrun += rsum;
    // pack P fragments (lane-local; order matches permuted V layout)
    f16x8 pf[4];
#pragma unroll
    for (int ks = 0; ks < 4; ++ks)
#pragma unroll
      for (int e = 0; e < 8; ++e) pf[ks][e] = (f16)s[2 * ks + (e >> 2)][e & 3];
    // O^T[d][q] += V^T_perm @ P  (A = V rows d from LDS, B = pf in-register)
    __builtin_amdgcn_s_setprio(1);
#pragma unroll
    for (int ks = 0; ks < 4; ++ks) {
      const f16* Vs = V0 + (ks >> 1) * 4096;         // 64-key sub-tile
      f16x8 vf[4];
#pragma unroll
      for (int mi = 0; mi < 4; ++mi) {
        int r = mi * 16 + q15;                       // d row 0..63
        int ke = ((ks & 1) * 32 + (g << 3)) ^ ((r & 7) << 3);
        vf[mi] = *(const f16x8*)&Vs[r * 64 + ke];
      }
#pragma unroll
      for (int mi = 0; mi < 4; ++mi) oacc[mi] = MFMA16(vf[mi], pf[ks], oacc[mi]);
    }
    __builtin_amdgcn_s_setprio(0);
    __syncthreads();  // staging for next tile complete; reads of cur done in all waves
  }
  // epilogue: O^T[d][q] -> Ob[q, d]; d = 16*mi + 4*g + reg (4 contiguous per mi)
  float inv = 1.0f / lrun;
  int gq = wq0 + q15;
#pragma unroll
  for (int mi = 0; mi < 4; ++mi) {
    f16x4 o4;
#pragma unroll
    for (int reg = 0; reg < 4; ++reg) o4[reg] = (f16)(oacc[mi][reg] * inv);
    *(f16x4*)&Ob[(size_t)gq * 1024 + mi * 16 + g * 4] = o4;
  }
}

// 1D grid, XCD-chunked (T1): XCD c = w&7 exclusively owns heads bh in [4c, 4c+4),
// so each XCD's L2 working set is 4 heads * (K+V = 512 KB) = 2 MB < 4 MB.
// Pair-balanced q-tiles {31-x, x}: uniform 17 128-key KV tiles per block, 2 blocks/CU.
__global__ __launch_bounds__(256, 2) void attn(const f16* __restrict__ Q,
                                               const f16* __restrict__ K,
                                               const f16* __restrict__ Vt,
                                               f16* __restrict__ O) {
  __shared__ __align__(16) f16 lK[2 * 8192];
  __shared__ __align__(16) f16 lV[2 * 8192];
  int w = blockIdx.x;            // 0..511
  int c = w & 7, j = w >> 3;     // XCD chunk id, index within chunk
  int bh = c * 4 + (j >> 4);     // 4 heads per XCD
  int x = j & 15;                // pair index within head
  int b = bh >> 4, h = bh & 15;
  int lane = threadIdx.x & 63, wave = threadIdx.x >> 6;
  const f16* Qb = Q + (size_t)bh * 2048 * 64;
  const f16* Kb = K + (size_t)bh * 2048 * 64;
  const f16* Vb = Vt + (size_t)bh * 2048 * 64;
  f16* Ob = O + (size_t)b * 2048 * 1024 + h * 64;
  attn_one(Qb, Kb, Vb, Ob, 31 - x, lane, wave, lK, lV);
  attn_one(Qb, Kb, Vb, Ob, x, lane, wave, lK, lV);
}

// ---------------- output projection ----------------
// Grid: 1D 256, XCD-chunked: XCD (w&7) owns 4bm x 8bn.
__global__ __launch_bounds__(256, 2) void gemm_out(const f16* __restrict__ A,
                                                   const f16* __restrict__ Bt,
                                                   const float* __restrict__ bias,
                                                   float* __restrict__ out) {
  __shared__ __align__(16) f16 lA[2 * 8192];
  __shared__ __align__(16) f16 lB[2 * 8192];
  f32x4 acc[4][4] = {};
  int w = blockIdx.x;           // 0..255
  int xcd = w & 7, i = w >> 3;  // [0,32)
  int bm = xcd * 4 + (i & 3);   // [0,32)
  int bn = i >> 2;              // [0,8)
  gemm_core<1024>(A, Bt, bm, bn, lA, lB, acc);
  int lane = threadIdx.x & 63, wave = threadIdx.x >> 6;
  int wm = wave >> 1, wn = wave & 1;
#pragma unroll
  for (int mi = 0; mi < 4; ++mi)
#pragma unroll
    for (int ni = 0; ni < 4; ++ni)
#pragma unroll
      for (int reg = 0; reg < 4; ++reg) {
        int gr = bm * 128 + wm * 64 + mi * 16 + ((lane >> 4) << 2) + reg;
        int gc = bn * 128 + wn * 64 + ni * 16 + (lane & 15);
        out[(size_t)gr * 1024 + gc] = acc[mi][ni][reg] + bias[gc];
      }
}

// ---------------- launcher ----------------
extern "C" void kernel_launch(void* const* d_in, const int* in_sizes, int n_in,
                              void* d_out, int out_size, void* d_ws, size_t ws_size,
                              hipStream_t stream) {
  const float* x     = (const float*)d_in[0];  // [2,2048,1024]
  const float* w_qkv = (const float*)d_in[1];  // [1024,3072]
  const float* w_out = (const float*)d_in[2];  // [1024,1024]
  const float* b_out = (const float*)d_in[3];  // [1024]
  // d_in[4] = attn_mask (causal; computed analytically)
  float* out = (float*)d_out;
  char* ws = (char*)d_ws;

  f16* xh    = (f16*)(ws);                   //  8 MB [4096,1024]
  f16* wqkvT = (f16*)(ws + (8u << 20));      //  6 MB [3072,1024]
  f16* woutT = (f16*)(ws + (14u << 20));     //  2 MB [1024,1024]
  f16* Qs    = (f16*)(ws + (16u << 20));     //  8 MB [B,H,N,D] (pre-scaled, log2-domain)
  f16* Ks    = (f16*)(ws + (24u << 20));     //  8 MB [B,H,N,D]
  f16* Vts   = (f16*)(ws + (32u << 20));     //  8 MB [B,H,D,N] (key-permuted)
  f16* Oa    = (f16*)(ws + (40u << 20));     //  8 MB [B,N,H*D]

  cast_f32_f16<<<4096, 256, 0, stream>>>(x, xh, 1048576);
  transpose_cast<<<dim3(96, 32), dim3(32, 8), 0, stream>>>(w_qkv, wqkvT, 1024, 3072);
  transpose_cast<<<dim3(32, 32), dim3(32, 8), 0, stream>>>(w_out, woutT, 1024, 1024);
  gemm_qkv<<<768, 256, 0, stream>>>(xh, wqkvT, Qs, Ks, Vts);
  attn<<<512, 256, 0, stream>>>(Qs, Ks, Vts, Oa);
  gemm_out<<<256, 256, 0, stream>>>(Oa, woutT, b_out, out);
}

// Round 9
// 118.637 us; speedup vs baseline: 1.0066x; 1.0066x over previous
//
#include <hip/hip_runtime.h>

typedef _Float16 f16;
typedef _Float16 f16x8 __attribute__((ext_vector_type(8)));
typedef _Float16 f16x4 __attribute__((ext_vector_type(4)));
typedef float    f32x4 __attribute__((ext_vector_type(4)));

#define MFMA16(a, b, c) __builtin_amdgcn_mfma_f32_16x16x32_f16((a), (b), (c), 0, 0, 0)

// async global->LDS, 16B per lane; LDS dest is wave-uniform base + lane*16
__device__ __forceinline__ void gload16(const void* g, void* l) {
  __builtin_amdgcn_global_load_lds(
      (const __attribute__((address_space(1))) unsigned int*)g,
      (__attribute__((address_space(3))) unsigned int*)l, 16, 0, 0);
}

// raw v_exp_f32: computes 2^x (scores are kept in log2 domain)
__device__ __forceinline__ float ex2(float x) {
  float r;
  asm("v_exp_f32 %0, %1" : "=v"(r) : "v"(x));
  return r;
}

// counted-vmcnt wait: N loads may stay outstanding (T4). "memory" clobber
// fences the compiler so LDS reads/stage issues don't cross it.
#define WAITV(N) asm volatile("s_waitcnt vmcnt(" #N ")" ::: "memory")
#define BARRIER() __builtin_amdgcn_s_barrier()
#define CFENCE() asm volatile("" ::: "memory")

// ---------------- prep kernels ----------------

__global__ void cast_f32_f16(const float* __restrict__ in, f16* __restrict__ out, int n4) {
  int i = blockIdx.x * blockDim.x + threadIdx.x;
  if (i < n4) {
    float4 v = ((const float4*)in)[i];
    f16x4 o;
    o.x = (f16)v.x; o.y = (f16)v.y; o.z = (f16)v.z; o.w = (f16)v.w;
    ((f16x4*)out)[i] = o;
  }
}

// out[c][r] = (f16) in[r][c];  R rows, Cc cols of `in`; both multiples of 32
__global__ void transpose_cast(const float* __restrict__ in, f16* __restrict__ out, int R, int Cc) {
  __shared__ float tile[32][33];
  int c0 = blockIdx.x * 32, r0 = blockIdx.y * 32;
  int tx = threadIdx.x, ty = threadIdx.y;
#pragma unroll
  for (int i = ty; i < 32; i += 8)
    tile[i][tx] = in[(size_t)(r0 + i) * Cc + c0 + tx];
  __syncthreads();
#pragma unroll
  for (int i = ty; i < 32; i += 8)
    out[(size_t)(c0 + i) * R + r0 + tx] = (f16)tile[tx][i];
}

// ---------------- shared GEMM core (double-buffered, counted vmcnt) ----------------
// C[128x128] tile = A[bm*128.., K] * Bt[bn*128.., K]^T, fp16 in, f32 acc.
// lA/lB: [2][128][64] f16. Schedule (m218 pattern): 2 stages in flight;
// per iter: vmcnt(8) [oldest stage done, newer 8 loads stay in flight ACROSS
// the barriers] -> barrier -> MFMA on cur -> barrier -> restage cur for kt+2.
// LDS content swizzle: LDS(row, kb) = global(row, kb ^ ((row&7)<<4)) bytes.
template <int KDIM>
__device__ __forceinline__ void gemm_core(const f16* __restrict__ A, const f16* __restrict__ Bt,
                                          int bm, int bn, f16* lA, f16* lB, f32x4 acc[4][4]) {
  const int t = threadIdx.x, lane = t & 63, wave = t >> 6;
  const int wm = wave >> 1, wn = wave & 1;
  const int srow = lane >> 3;            // row within 8-row chunk
  const int skb = (lane & 7) * 16;       // byte offset within 128B row
  const int nkt = KDIM / 64;

  auto STAGE = [&](int buf, int kt) {  // 8 gload16 per wave
#pragma unroll
    for (int c = 0; c < 4; ++c) {
      int cc = c * 4 + wave;             // 0..15, wave-uniform
      int row = cc * 8 + srow;           // 0..127
      int kbs = skb ^ ((row & 7) << 4);  // pre-swizzled source byte offset
      gload16((const char*)A + (size_t)(bm * 128 + row) * (KDIM * 2) + kt * 128 + kbs,
              lA + buf * 8192 + cc * 512);
      gload16((const char*)Bt + (size_t)(bn * 128 + row) * (KDIM * 2) + kt * 128 + kbs,
              lB + buf * 8192 + cc * 512);
    }
  };

  STAGE(0, 0);
  if (nkt > 1) STAGE(1, 1);
  for (int kt = 0; kt < nkt; ++kt) {
    int cur = kt & 1;
    if (kt + 1 < nkt) WAITV(8); else WAITV(0);
    BARRIER();  // buf cur complete in all waves; prior compute done
    const f16* A0 = lA + cur * 8192;
    const f16* B0 = lB + cur * 8192;
    __builtin_amdgcn_s_setprio(1);
#pragma unroll
    for (int ks = 0; ks < 2; ++ks) {
      f16x8 af[4], bf[4];
#pragma unroll
      for (int mi = 0; mi < 4; ++mi) {
        int r = wm * 64 + mi * 16 + (lane & 15);
        int ke = (ks * 32 + ((lane >> 4) << 3)) ^ ((r & 7) << 3);  // elements
        af[mi] = *(const f16x8*)&A0[r * 64 + ke];
      }
#pragma unroll
      for (int ni = 0; ni < 4; ++ni) {
        int r = wn * 64 + ni * 16 + (lane & 15);
        int ke = (ks * 32 + ((lane >> 4) << 3)) ^ ((r & 7) << 3);
        bf[ni] = *(const f16x8*)&B0[r * 64 + ke];
      }
#pragma unroll
      for (int mi = 0; mi < 4; ++mi)
#pragma unroll
        for (int ni = 0; ni < 4; ++ni)
          acc[mi][ni] = MFMA16(af[mi], bf[ni], acc[mi][ni]);
    }
    __builtin_amdgcn_s_setprio(0);
    BARRIER();  // all waves done reading cur
    CFENCE();
    if (kt + 2 < nkt) STAGE(cur, kt + 2);  // overwrite cur for step kt+2
  }
}

// ---------------- QKV projection ----------------
// A = x_f16 [4096,1024]; Bt = w_qkv^T [3072,1024].
// sec0 -> Q[B,H,N,D]*0.125*log2(e) (scores end up in log2 domain) ;
// sec1 -> K[B,H,N,D] ;
// sec2 -> V^T[B,H,D,N] with key index permuted within 32-blocks:
//   p(n) = 8*((n>>2)&3) + 4*((n>>4)&1) + (n&3)
// so that attention's PV B-fragment is lane-local (see attn_one).
// Grid: 1D 768, XCD-chunked: XCD (w&7) owns an 8bm x 12bn tile chunk.
__global__ __launch_bounds__(256, 2) void gemm_qkv(const f16* __restrict__ A,
                                                   const f16* __restrict__ Bt,
                                                   f16* __restrict__ Qo, f16* __restrict__ Ko,
                                                   f16* __restrict__ Vt) {
  __shared__ __align__(16) f16 lA[2 * 8192];
  __shared__ __align__(16) f16 lB[2 * 8192];
  f32x4 acc[4][4] = {};
  int w = blockIdx.x;            // 0..767
  int xcd = w & 7, i = w >> 3;   // i in [0,96)
  int xr = xcd >> 1, xc = xcd & 1;
  int bm = xr * 8 + (i & 7);     // [0,32)
  int bn = xc * 12 + (i >> 3);   // [0,24)
  gemm_core<1024>(A, Bt, bm, bn, lA, lB, acc);
  int lane = threadIdx.x & 63, wave = threadIdx.x >> 6;
  int wm = wave >> 1, wn = wave & 1;
  int sec = (bn * 128) >> 10;  // 0=Q 1=K 2=V, uniform per block (128 | 1024)
  float scl = (sec == 0) ? 0.18033688f : 1.0f;  // 0.125 * log2(e)
#pragma unroll
  for (int mi = 0; mi < 4; ++mi)
#pragma unroll
    for (int ni = 0; ni < 4; ++ni)
#pragma unroll
      for (int reg = 0; reg < 4; ++reg) {
        int gr = bm * 128 + wm * 64 + mi * 16 + ((lane >> 4) << 2) + reg;  // [0,4096)
        int gc = bn * 128 + wn * 64 + ni * 16 + (lane & 15);               // [0,3072)
        int b = gr >> 11, n = gr & 2047;
        int jj = gc & 1023;
        int h = jj >> 6, d = jj & 63;
        f16 v = (f16)(acc[mi][ni][reg] * scl);
        size_t bh = (size_t)(b * 16 + h);
        if (sec == 0)      Qo[(bh * 2048 + n) * 64 + d] = v;
        else if (sec == 1) Ko[(bh * 2048 + n) * 64 + d] = v;
        else {
          int np = (n & ~31) | (((n >> 2) & 3) << 3) | (((n >> 4) & 1) << 2) | (n & 3);
          Vt[(bh * 64 + d) * 2048 + np] = v;
        }
      }
}

// ---------------- causal flash attention ----------------
// Q pre-scaled by 0.125*log2e (log2-domain scores). Q,K: [B,H,N,D] f16;
// Vt: [B,H,D,N] f16 (key-permuted); Ob: [N,C] slice.
// KV tiles of 128 keys, double-buffered with counted vmcnt (same schedule as
// gemm_core). K LDS [128][64]; V LDS = two [64][64] sub-tiles; all row-swizzled.
// Swapped-operand: S^T = mfma(K, Q); q = lane&15, k = kv0 + 16*ni + 4*(lane>>4) + reg.
__device__ __forceinline__ void attn_one(const f16* __restrict__ Qb, const f16* __restrict__ Kb,
                                         const f16* __restrict__ Vb, f16* __restrict__ Ob,
                                         int qt, int lane, int wave, f16* lK, f16* lV) {
  const int N = 2048;
  const int wq0 = qt * 64 + wave * 16;
  const int g = lane >> 4, q15 = lane & 15;
  f16x8 qf[2];
#pragma unroll
  for (int ks = 0; ks < 2; ++ks)
    qf[ks] = *(const f16x8*)&Qb[(size_t)(wq0 + q15) * 64 + ks * 32 + (g << 3)];
  f32x4 oacc[4] = {};
  float mrun = -1e30f, lrun = 0.f;
  const int srow = lane >> 3, skb = (lane & 7) * 16;
  const int ntiles = (qt >> 1) + 1;  // 128-key tiles

  auto STAGE = [&](int buf, int kv) {  // 8 gload16 per wave
    int kv0 = kv << 7;
#pragma unroll
    for (int c = 0; c < 4; ++c) {
      int cc = c * 4 + wave;             // 0..15, wave-uniform
      {  // K: rows 0..127 (keys), 128B each
        int row = cc * 8 + srow;
        int kbs = skb ^ ((row & 7) << 4);
        gload16((const char*)Kb + (size_t)(kv0 + row) * 128 + kbs, lK + buf * 8192 + cc * 512);
      }
      {  // V: sub-tile sv (keys kv0+64sv..+63), rows d 0..63, 128B each
        int sv = cc >> 3, c8 = cc & 7;
        int row = c8 * 8 + srow;
        int kbs = skb ^ ((row & 7) << 4);
        gload16((const char*)Vb + (size_t)row * (N * 2) + (size_t)(kv0 + sv * 64) * 2 + kbs,
                lV + buf * 8192 + sv * 4096 + c8 * 512);
      }
    }
  };

  STAGE(0, 0);
  if (ntiles > 1) STAGE(1, 1);
  for (int kv = 0; kv < ntiles; ++kv) {
    int cur = kv & 1;
    if (kv + 1 < ntiles) WAITV(8); else WAITV(0);
    BARRIER();  // buf cur complete in all waves
    const f16* K0 = lK + cur * 8192;
    const f16* V0 = lV + cur * 8192;
    int kv0 = kv << 7;
    f32x4 s[8] = {};
    __builtin_amdgcn_s_setprio(1);
#pragma unroll
    for (int ks = 0; ks < 2; ++ks) {
      f16x8 kf[8];
#pragma unroll
      for (int ni = 0; ni < 8; ++ni) {
        int r = ni * 16 + q15;                       // key row 0..127
        int ke = (ks * 32 + (g << 3)) ^ ((r & 7) << 3);
        kf[ni] = *(const f16x8*)&K0[r * 64 + ke];
      }
#pragma unroll
      for (int ni = 0; ni < 8; ++ni) s[ni] = MFMA16(kf[ni], qf[ks], s[ni]);  // S^T[k][q]
    }
    __builtin_amdgcn_s_setprio(0);
    if (kv == ntiles - 1) {  // last tile: causal mask. k = kv0+16ni+4g+reg, q = wq0+q15.
      int gq = wq0 + q15;
#pragma unroll
      for (int ni = 0; ni < 8; ++ni)
#pragma unroll
        for (int reg = 0; reg < 4; ++reg) {
          int gk = kv0 + ni * 16 + g * 4 + reg;
          if (gk > gq) s[ni][reg] = -1e30f;
        }
    }
    // per-lane max over 32 regs + 2 shfl (lanes l, l+16, l+32, l+48 share q)
    f32x4 m4 = s[0];
#pragma unroll
    for (int ni = 1; ni < 8; ++ni)
#pragma unroll
      for (int reg = 0; reg < 4; ++reg) m4[reg] = fmaxf(m4[reg], s[ni][reg]);
    float mx = fmaxf(fmaxf(m4[0], m4[1]), fmaxf(m4[2], m4[3]));
    mx = fmaxf(mx, __shfl_xor(mx, 16));
    mx = fmaxf(mx, __shfl_xor(mx, 32));
    // T13: rescale only if some row's running max grew (wave-uniform)
    if (__any(mx > mrun)) {
      float mnew = fmaxf(mrun, mx);
      float corr = ex2(mrun - mnew);
      mrun = mnew;
      lrun *= corr;
#pragma unroll
      for (int ni = 0; ni < 4; ++ni)
#pragma unroll
        for (int reg = 0; reg < 4; ++reg) oacc[ni][reg] *= corr;
    }
    float rsum = 0.f;
#pragma unroll
    for (int ni = 0; ni < 8; ++ni)
#pragma unroll
      for (int reg = 0; reg < 4; ++reg) {
        float p = ex2(s[ni][reg] - mrun);
        s[ni][reg] = p;
        rsum += p;
      }
    rsum += __shfl_xor(rsum, 16);
    rsum += __shfl_xor(rsum, 32);
    lrun += rsum;
    // pack P fragments (lane-local; order matches permuted V layout)
    f16x8 pf[4];
#pragma unroll
    for (int ks = 0; ks < 4; ++ks)
#pragma unroll
      for (int e = 0; e < 8; ++e) pf[ks][e] = (f16)s[2 * ks + (e >> 2)][e & 3];
    // O^T[d][q] += V^T_perm @ P  (A = V rows d from LDS, B = pf in-register)
    __builtin_amdgcn_s_setprio(1);
#pragma unroll
    for (int ks = 0; ks < 4; ++ks) {
      const f16* Vs = V0 + (ks >> 1) * 4096;         // 64-key sub-tile
      f16x8 vf[4];
#pragma unroll
      for (int mi = 0; mi < 4; ++mi) {
        int r = mi * 16 + q15;                       // d row 0..63
        int ke = ((ks & 1) * 32 + (g << 3)) ^ ((r & 7) << 3);
        vf[mi] = *(const f16x8*)&Vs[r * 64 + ke];
      }
#pragma unroll
      for (int mi = 0; mi < 4; ++mi) oacc[mi] = MFMA16(vf[mi], pf[ks], oacc[mi]);
    }
    __builtin_amdgcn_s_setprio(0);
    BARRIER();  // all waves done reading cur
    CFENCE();
    if (kv + 2 < ntiles) STAGE(cur, kv + 2);
  }
  // epilogue: O^T[d][q] -> Ob[q, d]; d = 16*mi + 4*g + reg (4 contiguous per mi)
  float inv = 1.0f / lrun;
  int gq = wq0 + q15;
#pragma unroll
  for (int mi = 0; mi < 4; ++mi) {
    f16x4 o4;
#pragma unroll
    for (int reg = 0; reg < 4; ++reg) o4[reg] = (f16)(oacc[mi][reg] * inv);
    *(f16x4*)&Ob[(size_t)gq * 1024 + mi * 16 + g * 4] = o4;
  }
}

// 1D grid, XCD-chunked (T1): XCD c = w&7 exclusively owns heads bh in [4c, 4c+4),
// so each XCD's L2 working set is 4 heads * (K+V = 512 KB) = 2 MB < 4 MB.
// Pair-balanced q-tiles {31-x, x}: uniform 17 128-key KV tiles per block, 2 blocks/CU.
__global__ __launch_bounds__(256, 2) void attn(const f16* __restrict__ Q,
                                               const f16* __restrict__ K,
                                               const f16* __restrict__ Vt,
                                               f16* __restrict__ O) {
  __shared__ __align__(16) f16 lK[2 * 8192];
  __shared__ __align__(16) f16 lV[2 * 8192];
  int w = blockIdx.x;            // 0..511
  int c = w & 7, j = w >> 3;     // XCD chunk id, index within chunk
  int bh = c * 4 + (j >> 4);     // 4 heads per XCD
  int x = j & 15;                // pair index within head
  int b = bh >> 4, h = bh & 15;
  int lane = threadIdx.x & 63, wave = threadIdx.x >> 6;
  const f16* Qb = Q + (size_t)bh * 2048 * 64;
  const f16* Kb = K + (size_t)bh * 2048 * 64;
  const f16* Vb = Vt + (size_t)bh * 2048 * 64;
  f16* Ob = O + (size_t)b * 2048 * 1024 + h * 64;
  attn_one(Qb, Kb, Vb, Ob, 31 - x, lane, wave, lK, lV);
  attn_one(Qb, Kb, Vb, Ob, x, lane, wave, lK, lV);
}

// ---------------- output projection ----------------
// Grid: 1D 256, XCD-chunked: XCD (w&7) owns 4bm x 8bn.
__global__ __launch_bounds__(256, 2) void gemm_out(const f16* __restrict__ A,
                                                   const f16* __restrict__ Bt,
                                                   const float* __restrict__ bias,
                                                   float* __restrict__ out) {
  __shared__ __align__(16) f16 lA[2 * 8192];
  __shared__ __align__(16) f16 lB[2 * 8192];
  f32x4 acc[4][4] = {};
  int w = blockIdx.x;           // 0..255
  int xcd = w & 7, i = w >> 3;  // [0,32)
  int bm = xcd * 4 + (i & 3);   // [0,32)
  int bn = i >> 2;              // [0,8)
  gemm_core<1024>(A, Bt, bm, bn, lA, lB, acc);
  int lane = threadIdx.x & 63, wave = threadIdx.x >> 6;
  int wm = wave >> 1, wn = wave & 1;
#pragma unroll
  for (int mi = 0; mi < 4; ++mi)
#pragma unroll
    for (int ni = 0; ni < 4; ++ni)
#pragma unroll
      for (int reg = 0; reg < 4; ++reg) {
        int gr = bm * 128 + wm * 64 + mi * 16 + ((lane >> 4) << 2) + reg;
        int gc = bn * 128 + wn * 64 + ni * 16 + (lane & 15);
        out[(size_t)gr * 1024 + gc] = acc[mi][ni][reg] + bias[gc];
      }
}

// ---------------- launcher ----------------
extern "C" void kernel_launch(void* const* d_in, const int* in_sizes, int n_in,
                              void* d_out, int out_size, void* d_ws, size_t ws_size,
                              hipStream_t stream) {
  const float* x     = (const float*)d_in[0];  // [2,2048,1024]
  const float* w_qkv = (const float*)d_in[1];  // [1024,3072]
  const float* w_out = (const float*)d_in[2];  // [1024,1024]
  const float* b_out = (const float*)d_in[3];  // [1024]
  // d_in[4] = attn_mask (causal; computed analytically)
  float* out = (float*)d_out;
  char* ws = (char*)d_ws;

  f16* xh    = (f16*)(ws);                   //  8 MB [4096,1024]
  f16* wqkvT = (f16*)(ws + (8u << 20));      //  6 MB [3072,1024]
  f16* woutT = (f16*)(ws + (14u << 20));     //  2 MB [1024,1024]
  f16* Qs    = (f16*)(ws + (16u << 20));     //  8 MB [B,H,N,D] (pre-scaled, log2-domain)
  f16* Ks    = (f16*)(ws + (24u << 20));     //  8 MB [B,H,N,D]
  f16* Vts   = (f16*)(ws + (32u << 20));     //  8 MB [B,H,D,N] (key-permuted)
  f16* Oa    = (f16*)(ws + (40u << 20));     //  8 MB [B,N,H*D]

  cast_f32_f16<<<4096, 256, 0, stream>>>(x, xh, 1048576);
  transpose_cast<<<dim3(96, 32), dim3(32, 8), 0, stream>>>(w_qkv, wqkvT, 1024, 3072);
  transpose_cast<<<dim3(32, 32), dim3(32, 8), 0, stream>>>(w_out, woutT, 1024, 1024);
  gemm_qkv<<<768, 256, 0, stream>>>(xh, wqkvT, Qs, Ks, Vts);
  attn<<<512, 256, 0, stream>>>(Qs, Ks, Vts, Oa);
  gemm_out<<<256, 256, 0, stream>>>(Oa, woutT, b_out, out);
}

// Round 10
// 103.825 us; speedup vs baseline: 1.1502x; 1.1427x over previous
//
#include <hip/hip_runtime.h>

typedef _Float16 f16;
typedef _Float16 f16x8 __attribute__((ext_vector_type(8)));
typedef _Float16 f16x4 __attribute__((ext_vector_type(4)));
typedef float    f32x4 __attribute__((ext_vector_type(4)));

#define MFMA16(a, b, c) __builtin_amdgcn_mfma_f32_16x16x32_f16((a), (b), (c), 0, 0, 0)

// async global->LDS, 16B per lane; LDS dest is wave-uniform base + lane*16
__device__ __forceinline__ void gload16(const void* g, void* l) {
  __builtin_amdgcn_global_load_lds(
      (const __attribute__((address_space(1))) unsigned int*)g,
      (__attribute__((address_space(3))) unsigned int*)l, 16, 0, 0);
}

// raw v_exp_f32: computes 2^x (scores are kept in log2 domain)
__device__ __forceinline__ float ex2(float x) {
  float r;
  asm("v_exp_f32 %0, %1" : "=v"(r) : "v"(x));
  return r;
}

// counted-vmcnt wait: N loads may stay outstanding (T4). "memory" clobber
// fences the compiler so LDS reads/stage issues don't cross it.
#define WAITV(N) asm volatile("s_waitcnt vmcnt(" #N ")" ::: "memory")
#define BARRIER() __builtin_amdgcn_s_barrier()
#define CFENCE() asm volatile("" ::: "memory")

// ---------------- prep kernels ----------------

__global__ void cast_f32_f16(const float* __restrict__ in, f16* __restrict__ out, int n4) {
  int i = blockIdx.x * blockDim.x + threadIdx.x;
  if (i < n4) {
    float4 v = ((const float4*)in)[i];
    f16x4 o;
    o.x = (f16)v.x; o.y = (f16)v.y; o.z = (f16)v.z; o.w = (f16)v.w;
    ((f16x4*)out)[i] = o;
  }
}

// out[c][r] = (f16) in[r][c];  R rows, Cc cols of `in`; both multiples of 32
__global__ void transpose_cast(const float* __restrict__ in, f16* __restrict__ out, int R, int Cc) {
  __shared__ float tile[32][33];
  int c0 = blockIdx.x * 32, r0 = blockIdx.y * 32;
  int tx = threadIdx.x, ty = threadIdx.y;
#pragma unroll
  for (int i = ty; i < 32; i += 8)
    tile[i][tx] = in[(size_t)(r0 + i) * Cc + c0 + tx];
  __syncthreads();
#pragma unroll
  for (int i = ty; i < 32; i += 8)
    out[(size_t)(c0 + i) * R + r0 + tx] = (f16)tile[tx][i];
}

// ---------------- shared GEMM core (R6-proven: single 32KB buffer) ----------------
// C[128x128] tile = A[bm*128.., K] * Bt[bn*128.., K]^T, K = KDIM, fp16 in, f32 acc.
// LDS layout: [row][64] f16, content swizzled: LDS(row, kb) = global(row, kb ^ ((row&7)<<4)).
// 3 blocks/CU co-resident (grid 768) overlap each other's barrier drains.
template <int KDIM>
__device__ __forceinline__ void gemm_core(const f16* __restrict__ A, const f16* __restrict__ Bt,
                                          int bm, int bn, f16* lA, f16* lB, f32x4 acc[4][4]) {
  const int t = threadIdx.x, lane = t & 63, wave = t >> 6;
  const int wm = wave >> 1, wn = wave & 1;
  const int srow = lane >> 3;            // row within 8-row chunk
  const int skb = (lane & 7) * 16;       // byte offset within 128B row
  const int nkt = KDIM / 64;
  for (int kt = 0; kt < nkt; ++kt) {
    __syncthreads();
#pragma unroll
    for (int c = 0; c < 4; ++c) {
      int cc = c * 4 + wave;             // 0..15, wave-uniform
      int row = cc * 8 + srow;           // 0..127
      int kbs = skb ^ ((row & 7) << 4);  // pre-swizzled source byte offset
      gload16((const char*)A + (size_t)(bm * 128 + row) * (KDIM * 2) + kt * 128 + kbs,
              lA + cc * 512);
      gload16((const char*)Bt + (size_t)(bn * 128 + row) * (KDIM * 2) + kt * 128 + kbs,
              lB + cc * 512);
    }
    __syncthreads();
#pragma unroll
    for (int ks = 0; ks < 2; ++ks) {
      f16x8 af[4], bf[4];
#pragma unroll
      for (int mi = 0; mi < 4; ++mi) {
        int r = wm * 64 + mi * 16 + (lane & 15);
        int ke = (ks * 32 + ((lane >> 4) << 3)) ^ ((r & 7) << 3);  // elements
        af[mi] = *(const f16x8*)&lA[r * 64 + ke];
      }
#pragma unroll
      for (int ni = 0; ni < 4; ++ni) {
        int r = wn * 64 + ni * 16 + (lane & 15);
        int ke = (ks * 32 + ((lane >> 4) << 3)) ^ ((r & 7) << 3);
        bf[ni] = *(const f16x8*)&lB[r * 64 + ke];
      }
#pragma unroll
      for (int mi = 0; mi < 4; ++mi)
#pragma unroll
        for (int ni = 0; ni < 4; ++ni)
          acc[mi][ni] = MFMA16(af[mi], bf[ni], acc[mi][ni]);
    }
  }
}

// ---------------- QKV projection ----------------
// A = x_f16 [4096,1024]; Bt = w_qkv^T [3072,1024].
// sec0 -> Q[B,H,N,D]*0.125*log2(e) ; sec1 -> K[B,H,N,D] ;
// sec2 -> V^T[B,H,D,N], key index permuted within 32-blocks (p5 below) so
// attention's PV B-fragment is lane-local. V^T is produced via an LDS
// transpose (permute applied at LDS-write) -> global stores are f16x8
// 16B-granule instead of a 64-lane 2B scatter.
// Grid: 1D 768, XCD-chunked: XCD (w&7) owns an 8bm x 12bn tile chunk.
__global__ __launch_bounds__(256, 2) void gemm_qkv(const f16* __restrict__ A,
                                                   const f16* __restrict__ Bt,
                                                   f16* __restrict__ Qo, f16* __restrict__ Ko,
                                                   f16* __restrict__ Vt) {
  __shared__ __align__(16) f16 smem[128 * 136];  // 34816 B; staging uses first 32KB
  f16* lA = smem;
  f16* lB = smem + 8192;
  f32x4 acc[4][4] = {};
  int w = blockIdx.x;            // 0..767
  int xcd = w & 7, i = w >> 3;   // i in [0,96)
  int xr = xcd >> 1, xc = xcd & 1;
  int bm = xr * 8 + (i & 7);     // [0,32)
  int bn = xc * 12 + (i >> 3);   // [0,24)
  gemm_core<1024>(A, Bt, bm, bn, lA, lB, acc);
  int lane = threadIdx.x & 63, wave = threadIdx.x >> 6;
  int wm = wave >> 1, wn = wave & 1;
  int g = lane >> 4, q15 = lane & 15;
  int sec = (bn * 128) >> 10;  // 0=Q 1=K 2=V, uniform per block (128 | 1024)
  if (sec < 2) {
    float scl = (sec == 0) ? 0.18033688f : 1.0f;  // 0.125 * log2(e)
#pragma unroll
    for (int mi = 0; mi < 4; ++mi)
#pragma unroll
      for (int ni = 0; ni < 4; ++ni)
#pragma unroll
        for (int reg = 0; reg < 4; ++reg) {
          int gr = bm * 128 + wm * 64 + mi * 16 + (g << 2) + reg;  // [0,4096)
          int gc = bn * 128 + wn * 64 + ni * 16 + q15;             // [0,3072)
          int b = gr >> 11, n = gr & 2047;
          int jj = gc & 1023;
          int h = jj >> 6, d = jj & 63;
          f16 v = (f16)(acc[mi][ni][reg] * scl);
          size_t bh = (size_t)(b * 16 + h);
          if (sec == 0) Qo[(bh * 2048 + n) * 64 + d] = v;
          else          Ko[(bh * 2048 + n) * 64 + d] = v;
        }
  } else {
    // V: acc(local row rl = n, local col cl = head*64+d) -> LDS[cl][p(rl)] -> coalesced V^T
    __syncthreads();  // all LDS reads of the K-loop complete before overwrite
#pragma unroll
    for (int mi = 0; mi < 4; ++mi)
#pragma unroll
      for (int ni = 0; ni < 4; ++ni)
#pragma unroll
        for (int reg = 0; reg < 4; ++reg) {
          int rl = wm * 64 + mi * 16 + (g << 2) + reg;  // local n 0..127
          int cl = wn * 64 + ni * 16 + q15;             // local col 0..127
          int r5 = rl & 31;
          int rlp = (rl & ~31) | (((r5 >> 2) & 3) << 3) | (((r5 >> 4) & 1) << 2) | (r5 & 3);
          smem[cl * 136 + rlp] = (f16)acc[mi][ni][reg];
        }
    __syncthreads();
    // write out: tid -> (cl = tid>>1, half = tid&1); 64 n per piece, linear
    int tid = threadIdx.x;
    int cl = tid >> 1, half = tid & 1;
    int jj = (bn * 128 + cl) & 1023;
    int h = jj >> 6, d = jj & 63;
    int b = (bm * 128) >> 11;
    size_t bh = (size_t)(b * 16 + h);
    f16* dst = Vt + (bh * 64 + d) * 2048 + (bm * 128 & 2047) + half * 64;
    const f16* src = smem + cl * 136 + half * 64;
#pragma unroll
    for (int j8 = 0; j8 < 8; ++j8)
      *(f16x8*)&dst[j8 * 8] = *(const f16x8*)&src[j8 * 8];
  }
}

// ---------------- causal flash attention ----------------
// Q pre-scaled by 0.125*log2e (log2-domain scores). Q,K: [B,H,N,D] f16;
// Vt: [B,H,D,N] f16 (key-permuted); Ob: [N,C] slice.
// KV tiles of 128 keys, double-buffered with counted vmcnt (T4): 2 stages in
// flight; vmcnt(8) retires the stage being consumed while the newer 8 loads
// stay in flight across both barriers. K LDS [128][64]; V LDS = two [64][64]
// sub-tiles; all row-swizzled (0-conflict).
// Swapped-operand: S^T = mfma(K, Q); q = lane&15, k = kv0 + 16*ni + 4*(lane>>4) + reg.
__device__ __forceinline__ void attn_one(const f16* __restrict__ Qb, const f16* __restrict__ Kb,
                                         const f16* __restrict__ Vb, f16* __restrict__ Ob,
                                         int qt, int lane, int wave, f16* lK, f16* lV) {
  const int N = 2048;
  const int wq0 = qt * 64 + wave * 16;
  const int g = lane >> 4, q15 = lane & 15;
  f16x8 qf[2];
#pragma unroll
  for (int ks = 0; ks < 2; ++ks)
    qf[ks] = *(const f16x8*)&Qb[(size_t)(wq0 + q15) * 64 + ks * 32 + (g << 3)];
  f32x4 oacc[4] = {};
  float mrun = -1e30f, lrun = 0.f;
  const int srow = lane >> 3, skb = (lane & 7) * 16;
  const int ntiles = (qt >> 1) + 1;  // 128-key tiles

  auto STAGE = [&](int buf, int kv) {  // 8 gload16 per wave
    int kv0 = kv << 7;
#pragma unroll
    for (int c = 0; c < 4; ++c) {
      int cc = c * 4 + wave;             // 0..15, wave-uniform
      {  // K: rows 0..127 (keys), 128B each
        int row = cc * 8 + srow;
        int kbs = skb ^ ((row & 7) << 4);
        gload16((const char*)Kb + (size_t)(kv0 + row) * 128 + kbs, lK + buf * 8192 + cc * 512);
      }
      {  // V: sub-tile sv (keys kv0+64sv..+63), rows d 0..63, 128B each
        int sv = cc >> 3, c8 = cc & 7;
        int row = c8 * 8 + srow;
        int kbs = skb ^ ((row & 7) << 4);
        gload16((const char*)Vb + (size_t)row * (N * 2) + (size_t)(kv0 + sv * 64) * 2 + kbs,
                lV + buf * 8192 + sv * 4096 + c8 * 512);
      }
    }
  };

  STAGE(0, 0);
  if (ntiles > 1) STAGE(1, 1);
  for (int kv = 0; kv < ntiles; ++kv) {
    int cur = kv & 1;
    if (kv + 1 < ntiles) WAITV(8); else WAITV(0);
    BARRIER();  // buf cur complete in all waves
    const f16* K0 = lK + cur * 8192;
    const f16* V0 = lV + cur * 8192;
    int kv0 = kv << 7;
    f32x4 s[8] = {};
    __builtin_amdgcn_s_setprio(1);
#pragma unroll
    for (int ks = 0; ks < 2; ++ks) {
      f16x8 kf[8];
#pragma unroll
      for (int ni = 0; ni < 8; ++ni) {
        int r = ni * 16 + q15;                       // key row 0..127
        int ke = (ks * 32 + (g << 3)) ^ ((r & 7) << 3);
        kf[ni] = *(const f16x8*)&K0[r * 64 + ke];
      }
#pragma unroll
      for (int ni = 0; ni < 8; ++ni) s[ni] = MFMA16(kf[ni], qf[ks], s[ni]);  // S^T[k][q]
    }
    __builtin_amdgcn_s_setprio(0);
    if (kv == ntiles - 1) {  // last tile: causal mask. k = kv0+16ni+4g+reg, q = wq0+q15.
      int gq = wq0 + q15;
#pragma unroll
      for (int ni = 0; ni < 8; ++ni)
#pragma unroll
        for (int reg = 0; reg < 4; ++reg) {
          int gk = kv0 + ni * 16 + g * 4 + reg;
          if (gk > gq) s[ni][reg] = -1e30f;
        }
    }
    // per-lane max over 32 regs + 2 shfl (lanes l, l+16, l+32, l+48 share q)
    f32x4 m4 = s[0];
#pragma unroll
    for (int ni = 1; ni < 8; ++ni)
#pragma unroll
      for (int reg = 0; reg < 4; ++reg) m4[reg] = fmaxf(m4[reg], s[ni][reg]);
    float mx = fmaxf(fmaxf(m4[0], m4[1]), fmaxf(m4[2], m4[3]));
    mx = fmaxf(mx, __shfl_xor(mx, 16));
    mx = fmaxf(mx, __shfl_xor(mx, 32));
    // T13: rescale only if some row's running max grew (wave-uniform)
    if (__any(mx > mrun)) {
      float mnew = fmaxf(mrun, mx);
      float corr = ex2(mrun - mnew);
      mrun = mnew;
      lrun *= corr;
#pragma unroll
      for (int ni = 0; ni < 4; ++ni)
#pragma unroll
        for (int reg = 0; reg < 4; ++reg) oacc[ni][reg] *= corr;
    }
    float rsum = 0.f;
#pragma unroll
    for (int ni = 0; ni < 8; ++ni)
#pragma unroll
      for (int reg = 0; reg < 4; ++reg) {
        float p = ex2(s[ni][reg] - mrun);
        s[ni][reg] = p;
        rsum += p;
      }
    rsum += __shfl_xor(rsum, 16);
    rsum += __shfl_xor(rsum, 32);
    lrun += rsum;
    // pack P fragments (lane-local; order matches permuted V layout)
    f16x8 pf[4];
#pragma unroll
    for (int ks = 0; ks < 4; ++ks)
#pragma unroll
      for (int e = 0; e < 8; ++e) pf[ks][e] = (f16)s[2 * ks + (e >> 2)][e & 3];
    // O^T[d][q] += V^T_perm @ P  (A = V rows d from LDS, B = pf in-register)
    __builtin_amdgcn_s_setprio(1);
#pragma unroll
    for (int ks = 0; ks < 4; ++ks) {
      const f16* Vs = V0 + (ks >> 1) * 4096;         // 64-key sub-tile
      f16x8 vf[4];
#pragma unroll
      for (int mi = 0; mi < 4; ++mi) {
        int r = mi * 16 + q15;                       // d row 0..63
        int ke = ((ks & 1) * 32 + (g << 3)) ^ ((r & 7) << 3);
        vf[mi] = *(const f16x8*)&Vs[r * 64 + ke];
      }
#pragma unroll
      for (int mi = 0; mi < 4; ++mi) oacc[mi] = MFMA16(vf[mi], pf[ks], oacc[mi]);
    }
    __builtin_amdgcn_s_setprio(0);
    BARRIER();  // all waves done reading cur
    CFENCE();
    if (kv + 2 < ntiles) STAGE(cur, kv + 2);
  }
  // epilogue: O^T[d][q] -> Ob[q, d]; d = 16*mi + 4*g + reg (4 contiguous per mi)
  float inv = 1.0f / lrun;
  int gq = wq0 + q15;
#pragma unroll
  for (int mi = 0; mi < 4; ++mi) {
    f16x4 o4;
#pragma unroll
    for (int reg = 0; reg < 4; ++reg) o4[reg] = (f16)(oacc[mi][reg] * inv);
    *(f16x4*)&Ob[(size_t)gq * 1024 + mi * 16 + g * 4] = o4;
  }
}

// 1D grid, XCD-chunked (T1): XCD c = w&7 exclusively owns heads bh in [4c, 4c+4),
// so each XCD's L2 working set is 4 heads * (K+V = 512 KB) = 2 MB < 4 MB.
// Pair-balanced q-tiles {31-x, x}: uniform 17 128-key KV tiles per block, 2 blocks/CU.
__global__ __launch_bounds__(256, 2) void attn(const f16* __restrict__ Q,
                                               const f16* __restrict__ K,
                                               const f16* __restrict__ Vt,
                                               f16* __restrict__ O) {
  __shared__ __align__(16) f16 lK[2 * 8192];
  __shared__ __align__(16) f16 lV[2 * 8192];
  int w = blockIdx.x;            // 0..511
  int c = w & 7, j = w >> 3;     // XCD chunk id, index within chunk
  int bh = c * 4 + (j >> 4);     // 4 heads per XCD
  int x = j & 15;                // pair index within head
  int b = bh >> 4, h = bh & 15;
  int lane = threadIdx.x & 63, wave = threadIdx.x >> 6;
  const f16* Qb = Q + (size_t)bh * 2048 * 64;
  const f16* Kb = K + (size_t)bh * 2048 * 64;
  const f16* Vb = Vt + (size_t)bh * 2048 * 64;
  f16* Ob = O + (size_t)b * 2048 * 1024 + h * 64;
  attn_one(Qb, Kb, Vb, Ob, 31 - x, lane, wave, lK, lV);
  attn_one(Qb, Kb, Vb, Ob, x, lane, wave, lK, lV);
}

// ---------------- output projection ----------------
// Grid: 1D 256, XCD-chunked: XCD (w&7) owns 4bm x 8bn.
__global__ __launch_bounds__(256, 2) void gemm_out(const f16* __restrict__ A,
                                                   const f16* __restrict__ Bt,
                                                   const float* __restrict__ bias,
                                                   float* __restrict__ out) {
  __shared__ __align__(16) f16 lA[128 * 64];
  __shared__ __align__(16) f16 lB[128 * 64];
  f32x4 acc[4][4] = {};
  int w = blockIdx.x;           // 0..255
  int xcd = w & 7, i = w >> 3;  // [0,32)
  int bm = xcd * 4 + (i & 3);   // [0,32)
  int bn = i >> 2;              // [0,8)
  gemm_core<1024>(A, Bt, bm, bn, lA, lB, acc);
  int lane = threadIdx.x & 63, wave = threadIdx.x >> 6;
  int wm = wave >> 1, wn = wave & 1;
#pragma unroll
  for (int mi = 0; mi < 4; ++mi)
#pragma unroll
    for (int ni = 0; ni < 4; ++ni)
#pragma unroll
      for (int reg = 0; reg < 4; ++reg) {
        int gr = bm * 128 + wm * 64 + mi * 16 + ((lane >> 4) << 2) + reg;
        int gc = bn * 128 + wn * 64 + ni * 16 + (lane & 15);
        out[(size_t)gr * 1024 + gc] = acc[mi][ni][reg] + bias[gc];
      }
}

// ---------------- launcher ----------------
extern "C" void kernel_launch(void* const* d_in, const int* in_sizes, int n_in,
                              void* d_out, int out_size, void* d_ws, size_t ws_size,
                              hipStream_t stream) {
  const float* x     = (const float*)d_in[0];  // [2,2048,1024]
  const float* w_qkv = (const float*)d_in[1];  // [1024,3072]
  const float* w_out = (const float*)d_in[2];  // [1024,1024]
  const float* b_out = (const float*)d_in[3];  // [1024]
  // d_in[4] = attn_mask (causal; computed analytically)
  float* out = (float*)d_out;
  char* ws = (char*)d_ws;

  f16* xh    = (f16*)(ws);                   //  8 MB [4096,1024]
  f16* wqkvT = (f16*)(ws + (8u << 20));      //  6 MB [3072,1024]
  f16* woutT = (f16*)(ws + (14u << 20));     //  2 MB [1024,1024]
  f16* Qs    = (f16*)(ws + (16u << 20));     //  8 MB [B,H,N,D] (pre-scaled, log2-domain)
  f16* Ks    = (f16*)(ws + (24u << 20));     //  8 MB [B,H,N,D]
  f16* Vts   = (f16*)(ws + (32u << 20));     //  8 MB [B,H,D,N] (key-permuted)
  f16* Oa    = (f16*)(ws + (40u << 20));     //  8 MB [B,N,H*D]

  cast_f32_f16<<<4096, 256, 0, stream>>>(x, xh, 1048576);
  transpose_cast<<<dim3(96, 32), dim3(32, 8), 0, stream>>>(w_qkv, wqkvT, 1024, 3072);
  transpose_cast<<<dim3(32, 32), dim3(32, 8), 0, stream>>>(w_out, woutT, 1024, 1024);
  gemm_qkv<<<768, 256, 0, stream>>>(xh, wqkvT, Qs, Ks, Vts);
  attn<<<512, 256, 0, stream>>>(Qs, Ks, Vts, Oa);
  gemm_out<<<256, 256, 0, stream>>>(Oa, woutT, b_out, out);
}